// Round 1
// baseline (5133.152 us; speedup 1.0000x reference)
//
#include <hip/hip_runtime.h>

#define DIM 64
#define HID 256
#define NSTEPS 100
#define DT (1.0f / 100.0f)

typedef __attribute__((ext_vector_type(8))) short short8;   // 8 bf16 = 4 VGPRs (MFMA A/B frag)
typedef __attribute__((ext_vector_type(4))) float floatx4;  // MFMA C/D frag

__device__ __forceinline__ unsigned short f2bf(float f) {
  union { float f; unsigned int u; } v; v.f = f;
  unsigned int u = v.u;
  return (unsigned short)((u + 0x7fffu + ((u >> 16) & 1u)) >> 16);  // RNE
}

__device__ __forceinline__ float fast_tanh(float x) {
  // tanh(x) = 1 - 2/(e^{2x}+1); exp->inf => 1, exp->0 => -1 (correct saturation)
  float e = __expf(2.0f * x);
  return 1.0f - 2.0f * __builtin_amdgcn_rcpf(e + 1.0f);
}

// Repack W (K x N row-major fp32) into B-fragment-major bf16:
// element index = ((s*ntiles + t)*64 + lane)*8 + j
// holds B[k = s*32 + (lane>>4)*8 + j][n = t*16 + (lane&15)]
__global__ void prep_weights(const float* __restrict__ W1,
                             const float* __restrict__ W2,
                             const float* __restrict__ W3,
                             unsigned short* __restrict__ ws) {
  int e = blockIdx.x * 256 + threadIdx.x;  // 98304 total
  const float* src; int N, ntile, el, base;
  if (e < 16384)      { src = W1; N = 256; ntile = 16; base = 0;     el = e; }
  else if (e < 81920) { src = W2; N = 256; ntile = 16; base = 16384; el = e - 16384; }
  else                { src = W3; N = 64;  ntile = 4;  base = 81920; el = e - 81920; }
  int j = el & 7;
  int l = (el >> 3) & 63;
  int rem = el >> 9;
  int t = rem % ntile;
  int s = rem / ntile;
  int k = s * 32 + ((l >> 4) << 3) + j;
  int n = t * 16 + (l & 15);
  ws[base + el] = f2bf(src[k * N + n]);
}

__global__ __launch_bounds__(256, 2)
void cnf_kernel(const float* __restrict__ z0,
                const float* __restrict__ b1,
                const float* __restrict__ b2,
                const float* __restrict__ b3,
                const unsigned short* __restrict__ wsAll,
                float* __restrict__ out) {
  constexpr int LDZ = 72;   // 64 + 8 pad (keeps 16B align, breaks bank stride)
  constexpr int LDH = 264;  // 256 + 8 pad
  __shared__ __align__(16) unsigned short Zbuf[64 * LDZ];   // 9216 B
  __shared__ __align__(16) unsigned short Hbuf[64 * LDH];   // 33792 B
  __shared__ __align__(16) unsigned short Wstage[8192];     // 16384 B

  const int tid  = threadIdx.x;
  const int wave = tid >> 6;
  const int lane = tid & 63;
  const int ln15 = lane & 15;
  const int q8   = (lane >> 4) * 8;          // A-frag k sub-offset
  const int w16  = wave * 16;
  const int arow = w16 + ln15;               // A-frag row (m) for this lane
  const int wrow = w16 + (lane >> 4) * 4;    // C-layout base row for this lane
  const int grow = blockIdx.x * 64;

  const unsigned short* wsW1 = wsAll;
  const unsigned short* wsW2 = wsAll + 16384;
  const unsigned short* wsW3 = wsAll + 81920;

  // Biases resident in registers (C-layout columns: t*16 + ln15)
  float b1r[16], b2r[16], b3r[4];
#pragma unroll
  for (int t = 0; t < 16; ++t) { b1r[t] = b1[t * 16 + ln15]; b2r[t] = b2[t * 16 + ln15]; }
#pragma unroll
  for (int t = 0; t < 4; ++t)  b3r[t] = b3[t * 16 + ln15];

  // Master z (fp32, C-layout) + initial Zbuf (bf16, A-layout = row-major [m][k])
  float z[16], zacc[16];
#pragma unroll
  for (int t = 0; t < 4; ++t)
#pragma unroll
    for (int r = 0; r < 4; ++r) {
      float v = z0[(grow + wrow + r) * DIM + t * 16 + ln15];
      z[t * 4 + r] = v;
      zacc[t * 4 + r] = 0.f;
      Zbuf[(wrow + r) * LDZ + t * 16 + ln15] = f2bf(v);
    }

  const float DT6 = DT / 6.0f, DT3 = DT / 3.0f, DTH = 0.5f * DT;

  for (int step = 0; step < NSTEPS; ++step) {
#pragma unroll 1
    for (int st = 0; st < 4; ++st) {
      // ================= f(z_stage): Zbuf -> kreg =================
      // ---- Layer 1: H1 = tanh(Z @ W1 + b1), K=64, N=256
      floatx4 acc[16];
#pragma unroll
      for (int t = 0; t < 16; ++t) acc[t] = floatx4{0.f, 0.f, 0.f, 0.f};
#pragma unroll 1
      for (int s = 0; s < 2; ++s) {
        __syncthreads();
        {
          const uint4* s4 = (const uint4*)(wsW1 + s * 8192);
          uint4* d4 = (uint4*)Wstage;
#pragma unroll
          for (int i = 0; i < 4; ++i) d4[tid + 256 * i] = s4[tid + 256 * i];
        }
        __syncthreads();
        short8 af = *(const short8*)&Zbuf[arow * LDZ + s * 32 + q8];
#pragma unroll
        for (int t = 0; t < 16; ++t) {
          short8 bfr = *(const short8*)&Wstage[(t * 64 + lane) * 8];
          acc[t] = __builtin_amdgcn_mfma_f32_16x16x32_bf16(af, bfr, acc[t], 0, 0, 0);
        }
      }
#pragma unroll
      for (int t = 0; t < 16; ++t)
#pragma unroll
        for (int r = 0; r < 4; ++r) {
          float h = fast_tanh(acc[t][r] + b1r[t]);
          Hbuf[(wrow + r) * LDH + t * 16 + ln15] = f2bf(h);
        }

      // ---- Layer 2: H2 = tanh(H1 @ W2 + b2), K=256, N=256
#pragma unroll
      for (int t = 0; t < 16; ++t) acc[t] = floatx4{0.f, 0.f, 0.f, 0.f};
#pragma unroll 1
      for (int s = 0; s < 8; ++s) {
        __syncthreads();
        {
          const uint4* s4 = (const uint4*)(wsW2 + s * 8192);
          uint4* d4 = (uint4*)Wstage;
#pragma unroll
          for (int i = 0; i < 4; ++i) d4[tid + 256 * i] = s4[tid + 256 * i];
        }
        __syncthreads();
        short8 af = *(const short8*)&Hbuf[arow * LDH + s * 32 + q8];
#pragma unroll
        for (int t = 0; t < 16; ++t) {
          short8 bfr = *(const short8*)&Wstage[(t * 64 + lane) * 8];
          acc[t] = __builtin_amdgcn_mfma_f32_16x16x32_bf16(af, bfr, acc[t], 0, 0, 0);
        }
      }
      // overwrite own rows of Hbuf with H2 (wave-private: no barrier needed)
#pragma unroll
      for (int t = 0; t < 16; ++t)
#pragma unroll
        for (int r = 0; r < 4; ++r) {
          float h = fast_tanh(acc[t][r] + b2r[t]);
          Hbuf[(wrow + r) * LDH + t * 16 + ln15] = f2bf(h);
        }

      // ---- Layer 3: k = H2 @ W3 + b3, K=256, N=64
      floatx4 acc3[4];
#pragma unroll
      for (int t = 0; t < 4; ++t) acc3[t] = floatx4{0.f, 0.f, 0.f, 0.f};
#pragma unroll 1
      for (int sc = 0; sc < 2; ++sc) {
        __syncthreads();
        {
          const uint4* s4 = (const uint4*)(wsW3 + sc * 8192);
          uint4* d4 = (uint4*)Wstage;
#pragma unroll
          for (int i = 0; i < 4; ++i) d4[tid + 256 * i] = s4[tid + 256 * i];
        }
        __syncthreads();
#pragma unroll
        for (int ss = 0; ss < 4; ++ss) {
          short8 af = *(const short8*)&Hbuf[arow * LDH + (sc * 4 + ss) * 32 + q8];
#pragma unroll
          for (int t = 0; t < 4; ++t) {
            short8 bfr = *(const short8*)&Wstage[((ss * 4 + t) * 64 + lane) * 8];
            acc3[t] = __builtin_amdgcn_mfma_f32_16x16x32_bf16(af, bfr, acc3[t], 0, 0, 0);
          }
        }
      }

      // ================= RK4 combine (uniform branches on st) =================
      const float wsum = (st == 0 || st == 3) ? DT6 : DT3;
      const float cst  = (st == 2) ? DT : DTH;
      const bool  last = (st == 3);
      const bool  first = (st == 0);
#pragma unroll
      for (int t = 0; t < 4; ++t)
#pragma unroll
        for (int r = 0; r < 4; ++r) {
          int i = t * 4 + r;
          float k = acc3[t][r] + b3r[t];
          float za = first ? z[i] : zacc[i];
          za += wsum * k;
          zacc[i] = za;
          float stg;
          if (last) { z[i] = za; stg = za; }
          else      { stg = z[i] + cst * k; }
          Zbuf[(wrow + r) * LDZ + t * 16 + ln15] = f2bf(stg);
        }
    }
  }

  // Final store (fp32)
#pragma unroll
  for (int t = 0; t < 4; ++t)
#pragma unroll
    for (int r = 0; r < 4; ++r)
      out[(grow + wrow + r) * DIM + t * 16 + ln15] = z[t * 4 + r];
}

extern "C" void kernel_launch(void* const* d_in, const int* in_sizes, int n_in,
                              void* d_out, int out_size, void* d_ws, size_t ws_size,
                              hipStream_t stream) {
  const float* z0 = (const float*)d_in[0];
  const float* W1 = (const float*)d_in[1];
  const float* b1 = (const float*)d_in[2];
  const float* W2 = (const float*)d_in[3];
  const float* b2 = (const float*)d_in[4];
  const float* W3 = (const float*)d_in[5];
  const float* b3 = (const float*)d_in[6];
  unsigned short* ws = (unsigned short*)d_ws;  // 98304 bf16 = 196608 B

  prep_weights<<<384, 256, 0, stream>>>(W1, W2, W3, ws);
  cnf_kernel<<<512, 256, 0, stream>>>(z0, b1, b2, b3, ws, (float*)d_out);
}

// Round 2
// 3727.060 us; speedup vs baseline: 1.3773x; 1.3773x over previous
//
#include <hip/hip_runtime.h>

#define DIM 64
#define HID 256
#define NSTEPS 100
#define DT (1.0f / 100.0f)

typedef __attribute__((ext_vector_type(8))) short short8;   // 8 bf16 = 4 VGPRs (MFMA A/B frag)
typedef __attribute__((ext_vector_type(4))) float floatx4;  // MFMA C/D frag

__device__ __forceinline__ unsigned short f2bf(float f) {
  union { float f; unsigned int u; } v; v.f = f;
  unsigned int u = v.u;
  return (unsigned short)((u + 0x7fffu + ((u >> 16) & 1u)) >> 16);  // RNE
}

__device__ __forceinline__ float fast_tanh(float x) {
  float e = __expf(2.0f * x);
  return 1.0f - 2.0f * __builtin_amdgcn_rcpf(e + 1.0f);
}

// Repack W (K x N row-major fp32) into B-fragment-major bf16:
// element index = ((s*ntiles + t)*64 + lane)*8 + j
// holds B[k = s*32 + (lane>>4)*8 + j][n = t*16 + (lane&15)]
__global__ void prep_weights(const float* __restrict__ W1,
                             const float* __restrict__ W2,
                             const float* __restrict__ W3,
                             unsigned short* __restrict__ ws) {
  int e = blockIdx.x * 256 + threadIdx.x;  // 98304 total
  const float* src; int N, ntile, el, base;
  if (e < 16384)      { src = W1; N = 256; ntile = 16; base = 0;     el = e; }
  else if (e < 81920) { src = W2; N = 256; ntile = 16; base = 16384; el = e - 16384; }
  else                { src = W3; N = 64;  ntile = 4;  base = 81920; el = e - 81920; }
  int j = el & 7;
  int l = (el >> 3) & 63;
  int rem = el >> 9;
  int t = rem % ntile;
  int s = rem / ntile;
  int k = s * 32 + ((l >> 4) << 3) + j;
  int n = t * 16 + (l & 15);
  ws[base + el] = f2bf(src[k * N + n]);
}

// 512 threads = 8 waves. Wave w owns L1/L2 output cols [32w,32w+32) (t-tiles 2w,2w+1).
// Waves 0-3 additionally own L3 col-tile t=w, the RK4 state z, and Zbuf writes.
// Weights live in registers (B-frag layout) for the whole kernel: no weight staging,
// 4 barriers per f-eval (was 24).
__global__ __launch_bounds__(512, 2)
void cnf_kernel(const float* __restrict__ z0,
                const float* __restrict__ b1,
                const float* __restrict__ b2,
                const float* __restrict__ b3,
                const unsigned short* __restrict__ wsAll,
                float* __restrict__ out) {
  constexpr int LDZ = 72;   // 64 + 8 pad (shorts): row stride 144B -> balanced banks
  constexpr int LDH = 264;  // 256 + 8 pad
  __shared__ __align__(16) unsigned short Zbuf[64 * LDZ];   // 9216 B
  __shared__ __align__(16) unsigned short Hbuf[64 * LDH];   // 33792 B  (total 43008 B)

  const int tid  = threadIdx.x;
  const int wave = tid >> 6;
  const int lane = tid & 63;
  const int ln15 = lane & 15;
  const int q    = lane >> 4;
  const int q8   = q * 8;
  const int grow = blockIdx.x * 64;

  const unsigned short* wsW1 = wsAll;
  const unsigned short* wsW2 = wsAll + 16384;
  const unsigned short* wsW3 = wsAll + 81920;

  // ---- register-resident weight fragments ----
  short8 w1f[2][2];   // [s][tt]
  short8 w2f[8][2];   // [s][tt]
  short8 w3f[8];      // [s]  (waves 0-3 only)
#pragma unroll
  for (int s = 0; s < 2; ++s)
#pragma unroll
    for (int tt = 0; tt < 2; ++tt)
      w1f[s][tt] = *(const short8*)&wsW1[((s * 16 + 2 * wave + tt) * 64 + lane) * 8];
#pragma unroll
  for (int s = 0; s < 8; ++s)
#pragma unroll
    for (int tt = 0; tt < 2; ++tt)
      w2f[s][tt] = *(const short8*)&wsW2[((s * 16 + 2 * wave + tt) * 64 + lane) * 8];
  if (wave < 4) {
#pragma unroll
    for (int s = 0; s < 8; ++s)
      w3f[s] = *(const short8*)&wsW3[((s * 4 + wave) * 64 + lane) * 8];
  } else {
#pragma unroll
    for (int s = 0; s < 8; ++s) w3f[s] = short8{0,0,0,0,0,0,0,0};
  }

  // biases (C-layout cols)
  float b1r[2], b2r[2];
#pragma unroll
  for (int tt = 0; tt < 2; ++tt) {
    b1r[tt] = b1[(2 * wave + tt) * 16 + ln15];
    b2r[tt] = b2[(2 * wave + tt) * 16 + ln15];
  }
  const float b3r = (wave < 4) ? b3[wave * 16 + ln15] : 0.f;

  // RK4 state: waves 0-3 own z cols [16w,16w+16) for all 64 rows
  float z[16], zacc[16];
  if (wave < 4) {
#pragma unroll
    for (int m = 0; m < 4; ++m)
#pragma unroll
      for (int r = 0; r < 4; ++r) {
        float v = z0[(grow + m * 16 + q * 4 + r) * DIM + wave * 16 + ln15];
        z[m * 4 + r] = v;
        zacc[m * 4 + r] = 0.f;
        Zbuf[(m * 16 + q * 4 + r) * LDZ + wave * 16 + ln15] = f2bf(v);
      }
  }

  const float DT6 = DT / 6.0f, DT3 = DT / 3.0f, DTH = 0.5f * DT;

#pragma unroll 1
  for (int it = 0; it < NSTEPS * 4; ++it) {
    const int st = it & 3;
    __syncthreads();  // B1: Zbuf stage visible; Hbuf free (prev L3 reads done)

    // ---- Layer 1: H1 = tanh(Z @ W1 + b1); K=64 ----
#pragma unroll
    for (int m = 0; m < 4; ++m) {
      floatx4 acc[2] = {floatx4{0.f,0.f,0.f,0.f}, floatx4{0.f,0.f,0.f,0.f}};
#pragma unroll
      for (int s = 0; s < 2; ++s) {
        short8 af = *(const short8*)&Zbuf[(m * 16 + ln15) * LDZ + s * 32 + q8];
#pragma unroll
        for (int tt = 0; tt < 2; ++tt)
          acc[tt] = __builtin_amdgcn_mfma_f32_16x16x32_bf16(af, w1f[s][tt], acc[tt], 0, 0, 0);
      }
#pragma unroll
      for (int tt = 0; tt < 2; ++tt)
#pragma unroll
        for (int r = 0; r < 4; ++r) {
          float h = fast_tanh(acc[tt][r] + b1r[tt]);
          Hbuf[(m * 16 + q * 4 + r) * LDH + (2 * wave + tt) * 16 + ln15] = f2bf(h);
        }
    }
    __syncthreads();  // B2: H1 visible

    // ---- Layer 2 MFMAs: H2acc = H1 @ W2; K=256 ----
    floatx4 acc2[4][2];
#pragma unroll
    for (int m = 0; m < 4; ++m)
#pragma unroll
      for (int tt = 0; tt < 2; ++tt) acc2[m][tt] = floatx4{0.f,0.f,0.f,0.f};
#pragma unroll
    for (int m = 0; m < 4; ++m)
#pragma unroll
      for (int s = 0; s < 8; ++s) {
        short8 af = *(const short8*)&Hbuf[(m * 16 + ln15) * LDH + s * 32 + q8];
#pragma unroll
        for (int tt = 0; tt < 2; ++tt)
          acc2[m][tt] = __builtin_amdgcn_mfma_f32_16x16x32_bf16(af, w2f[s][tt], acc2[m][tt], 0, 0, 0);
      }
    __syncthreads();  // B3: all L2 reads of H1 complete -> Hbuf may be overwritten

    // ---- H2 epilogue ----
#pragma unroll
    for (int m = 0; m < 4; ++m)
#pragma unroll
      for (int tt = 0; tt < 2; ++tt)
#pragma unroll
        for (int r = 0; r < 4; ++r) {
          float h = fast_tanh(acc2[m][tt][r] + b2r[tt]);
          Hbuf[(m * 16 + q * 4 + r) * LDH + (2 * wave + tt) * 16 + ln15] = f2bf(h);
        }
    __syncthreads();  // B4: H2 visible

    // ---- Layer 3 + RK4 (waves 0-3) ----
    if (wave < 4) {
      const float wsum  = (st == 0 || st == 3) ? DT6 : DT3;
      const float cst   = (st == 2) ? DT : DTH;
      const bool  last  = (st == 3);
      const bool  first = (st == 0);
#pragma unroll
      for (int m = 0; m < 4; ++m) {
        floatx4 a3 = floatx4{0.f,0.f,0.f,0.f};
#pragma unroll
        for (int s = 0; s < 8; ++s) {
          short8 af = *(const short8*)&Hbuf[(m * 16 + ln15) * LDH + s * 32 + q8];
          a3 = __builtin_amdgcn_mfma_f32_16x16x32_bf16(af, w3f[s], a3, 0, 0, 0);
        }
#pragma unroll
        for (int r = 0; r < 4; ++r) {
          int i = m * 4 + r;
          float k = a3[r] + b3r;
          float za = first ? z[i] : zacc[i];
          za += wsum * k;
          zacc[i] = za;
          float stg;
          if (last) { z[i] = za; stg = za; }
          else      { stg = z[i] + cst * k; }
          Zbuf[(m * 16 + q * 4 + r) * LDZ + wave * 16 + ln15] = f2bf(stg);
        }
      }
    }
  }

  if (wave < 4) {
#pragma unroll
    for (int m = 0; m < 4; ++m)
#pragma unroll
      for (int r = 0; r < 4; ++r)
        out[(grow + m * 16 + q * 4 + r) * DIM + wave * 16 + ln15] = z[m * 4 + r];
  }
}

extern "C" void kernel_launch(void* const* d_in, const int* in_sizes, int n_in,
                              void* d_out, int out_size, void* d_ws, size_t ws_size,
                              hipStream_t stream) {
  const float* z0 = (const float*)d_in[0];
  const float* W1 = (const float*)d_in[1];
  const float* b1 = (const float*)d_in[2];
  const float* W2 = (const float*)d_in[3];
  const float* b2 = (const float*)d_in[4];
  const float* W3 = (const float*)d_in[5];
  const float* b3 = (const float*)d_in[6];
  unsigned short* ws = (unsigned short*)d_ws;  // 98304 bf16 = 196608 B

  prep_weights<<<384, 256, 0, stream>>>(W1, W2, W3, ws);
  cnf_kernel<<<512, 512, 0, stream>>>(z0, b1, b2, b3, ws, (float*)d_out);
}